// Round 11
// baseline (42.091 us; speedup 1.0000x reference)
//
#include <hip/hip_runtime.h>
#include <math.h>

#define NBANDS 5
#define T_TILE 2
#define PFUNC_ELEMS (32*128*64*64)
#define LOG2E 1.4426950408889634f

// DPP quad-reduce (VALU pipe): 0xB1 = quad_perm[1,0,3,2] (xor1),
// 0x4E = quad_perm[2,3,0,1] (xor2). Row i lives on one aligned quad here.
#define DPP_ADD(x, ctrl) \
    ((x) + __int_as_float(__builtin_amdgcn_update_dpp(0, __float_as_int(x), (ctrl), 0xF, 0xF, true)))

__global__ __launch_bounds__(256) void bfp_kernel(
        const float* __restrict__ x,      // (32,5,64,128)
        const float* __restrict__ adj,    // (64,64), values in {0,1}
        const float* __restrict__ amask,  // (32,128,5)
        const float* __restrict__ alpha,  // (32,128,5)
        const float* __restrict__ We,     // (5,64)
        const float* __restrict__ be,     // (5,64)
        const float* __restrict__ Wq,     // (16,64)
        const float* __restrict__ Wk,     // (16,64)
        float* __restrict__ out) {
    // 2048 blocks; XCD-bijective swizzle (2048 % 8 == 0)
    const int bid = blockIdx.x;
    const int blk = (bid & 7) * 256 + (bid >> 3);
    const int bt0 = blk * T_TILE;
    const int b = bt0 >> 7;
    const int t0 = bt0 & 127;
    const int tid = threadIdx.x;

    __shared__ __align__(16) float x_s[T_TILE][NBANDS][64];
    __shared__ float xbar_s[T_TILE][NBANDS], xmax_s[T_TILE][NBANDS], xmin_s[T_TILE][NBANDS];
    __shared__ float w_s[T_TILE][NBANDS], mask_s[T_TILE][NBANDS];
    __shared__ float acw_s[NBANDS], bcw_s[NBANDS];

    const int i = tid >> 2;          // output row 0..63 (one aligned quad per row)
    const int j0 = (tid & 3) << 4;   // first of 16 owned columns

    // adjacency chunk: raw 0/1 floats used as multiplicative mask
    const float4 a0 = *(const float4*)(adj + i * 64 + j0);
    const float4 a1 = *(const float4*)(adj + i * 64 + j0 + 4);
    const float4 a2 = *(const float4*)(adj + i * 64 + j0 + 8);
    const float4 a3 = *(const float4*)(adj + i * 64 + j0 + 12);

    // stage x[b,n,c,t0..t0+1] -> x_s[t][n][c]; 320 float2 loads over 256 threads
    for (int idx = tid; idx < NBANDS * 64; idx += 256) {
        const int n = idx >> 6, c = idx & 63;
        float2 xv = *(const float2*)(x + ((size_t)b * 320 + idx) * 128 + t0);
        x_s[0][n][c] = xv.x;
        x_s[1][n][c] = xv.y;
    }
    // amask/alpha staging on the top threads
    if (tid >= 256 - T_TILE * NBANDS) {
        const int idx = tid - (256 - T_TILE * NBANDS);      // 0..9
        const size_t base = ((size_t)b * 128 + t0) * NBANDS;
        const int t = idx / NBANDS, n = idx % NBANDS;
        float mk = amask[base + idx];
        mask_s[t][n] = mk;
        w_s[t][n] = alpha[base + idx] * mk;
    }

    // fused prep on 4 waves: wave w does bands w and w+4 (only wave 0 repeats)
    {
        const int wvid = tid >> 6;
        const int lane = tid & 63;
        for (int n = wvid; n < NBANDS; n += 4) {
            const int s = lane >> 2;          // d_s index 0..15
            const int d0c = (lane & 3) * 16;  // d-chunk
            float u = 0.f, v = 0.f, w = 0.f;
            #pragma unroll
            for (int dd = 0; dd < 16; ++dd) {
                int d = d0c + dd;
                float we = We[n * 64 + d], bb = be[n * 64 + d];
                float wq = Wq[s * 64 + d], wk = Wk[s * 64 + d];
                u = fmaf(wq, we, u);   // A_s partial
                v = fmaf(wk, we, v);   // C_s partial
                w = fmaf(wq, bb, w);   // B_s partial
            }
            #pragma unroll
            for (int mk = 1; mk <= 2; mk <<= 1) {   // complete quads over d-chunks
                u += __shfl_xor(u, mk);
                v += __shfl_xor(v, mk);
                w += __shfl_xor(w, mk);
            }
            float ac = u * v, bc = w * v;           // A_s*C_s, B_s*C_s
            #pragma unroll
            for (int mk = 4; mk <= 32; mk <<= 1) {  // sum over the 16 s (each once)
                ac += __shfl_xor(ac, mk);
                bc += __shfl_xor(bc, mk);
            }
            if (lane == 0) {
                acw_s[n] = 0.25f * LOG2E * ac;  // 1/sqrt(d_s) * log2e folded
                bcw_s[n] = 0.25f * LOG2E * bc;
            }
        }
    }
    __syncthreads();

    // per-(t,band) sum/min/max over 64 electrodes; 10 pairs over 4 waves
    {
        const int wv = tid >> 6, lane = tid & 63;
        for (int pair = wv; pair < T_TILE * NBANDS; pair += 4) {
            const int t = pair & 1, n = pair >> 1;
            float v = x_s[t][n][lane];
            float sm = v, mx = v, mn = v;
            #pragma unroll
            for (int mk = 32; mk >= 1; mk >>= 1) {
                sm += __shfl_xor(sm, mk);
                mx = fmaxf(mx, __shfl_xor(mx, mk));
                mn = fminf(mn, __shfl_xor(mn, mk));
            }
            if (lane == 0) {
                xbar_s[t][n] = sm * (1.f / 64.f);
                xmax_s[t][n] = mx;
                xmin_s[t][n] = mn;
            }
        }
    }
    __syncthreads();

    // embeddings_mean for 2 t's (threads 0..127)
    if (tid < T_TILE * 64) {
        const int t = tid >> 6, d = tid & 63;
        float cnt = 0.f, accm = 0.f;
        #pragma unroll
        for (int n = 0; n < NBANDS; ++n) {
            cnt += mask_s[t][n];
            accm += mask_s[t][n] * fmaf(xbar_s[t][n], We[n * 64 + d], be[n * 64 + d]);
        }
        out[PFUNC_ELEMS + (size_t)(bt0 + t) * 64 + d] = accm / fmaxf(cnt, 1.f);
    }

    #pragma unroll
    for (int t = 0; t < T_TILE; ++t) {
        float acc[16];
        #pragma unroll
        for (int jj = 0; jj < 16; ++jj) acc[jj] = 0.f;

        #pragma unroll
        for (int n = 0; n < NBANDS; ++n) {
            // base-2 logits coefficient (0.25*log2e folded into acw/bcw)
            const float g2 = fmaf(acw_s[n], x_s[t][n][i], bcw_s[n]);
            // branchless conservative row bound over ALL j (unmasked exp2 safe)
            const float negm = -fmaxf(g2 * xmax_s[t][n], g2 * xmin_s[t][n]);
            const float4* xp = (const float4*)(&x_s[t][n][j0]);
            const float4 xv0 = xp[0], xv1 = xp[1], xv2 = xp[2], xv3 = xp[3];
            float e[16];
            e[0]  = __builtin_amdgcn_exp2f(fmaf(g2, xv0.x, negm));
            e[1]  = __builtin_amdgcn_exp2f(fmaf(g2, xv0.y, negm));
            e[2]  = __builtin_amdgcn_exp2f(fmaf(g2, xv0.z, negm));
            e[3]  = __builtin_amdgcn_exp2f(fmaf(g2, xv0.w, negm));
            e[4]  = __builtin_amdgcn_exp2f(fmaf(g2, xv1.x, negm));
            e[5]  = __builtin_amdgcn_exp2f(fmaf(g2, xv1.y, negm));
            e[6]  = __builtin_amdgcn_exp2f(fmaf(g2, xv1.z, negm));
            e[7]  = __builtin_amdgcn_exp2f(fmaf(g2, xv1.w, negm));
            e[8]  = __builtin_amdgcn_exp2f(fmaf(g2, xv2.x, negm));
            e[9]  = __builtin_amdgcn_exp2f(fmaf(g2, xv2.y, negm));
            e[10] = __builtin_amdgcn_exp2f(fmaf(g2, xv2.z, negm));
            e[11] = __builtin_amdgcn_exp2f(fmaf(g2, xv2.w, negm));
            e[12] = __builtin_amdgcn_exp2f(fmaf(g2, xv3.x, negm));
            e[13] = __builtin_amdgcn_exp2f(fmaf(g2, xv3.y, negm));
            e[14] = __builtin_amdgcn_exp2f(fmaf(g2, xv3.z, negm));
            e[15] = __builtin_amdgcn_exp2f(fmaf(g2, xv3.w, negm));
            // masked Z via four fma chains (mask folded here, NOT into acc)
            float z0 = e[0] * a0.x;
            z0 = fmaf(e[1], a0.y, z0); z0 = fmaf(e[2], a0.z, z0); z0 = fmaf(e[3], a0.w, z0);
            float z1 = e[4] * a1.x;
            z1 = fmaf(e[5], a1.y, z1); z1 = fmaf(e[6], a1.z, z1); z1 = fmaf(e[7], a1.w, z1);
            float z2 = e[8] * a2.x;
            z2 = fmaf(e[9], a2.y, z2); z2 = fmaf(e[10], a2.z, z2); z2 = fmaf(e[11], a2.w, z2);
            float z3 = e[12] * a3.x;
            z3 = fmaf(e[13], a3.y, z3); z3 = fmaf(e[14], a3.z, z3); z3 = fmaf(e[15], a3.w, z3);
            float Z = (z0 + z1) + (z2 + z3);
            Z = DPP_ADD(Z, 0xB1);    // + lane^1
            Z = DPP_ADD(Z, 0x4E);    // + lane^2  -> full 64-col row sum
            const float sc = w_s[t][n] * __builtin_amdgcn_rcpf(fmaxf(Z, 1e-30f));
            // unmasked accumulate; mask applied once at the store
            #pragma unroll
            for (int jj = 0; jj < 16; ++jj) acc[jj] = fmaf(e[jj], sc, acc[jj]);
        }

        float4* outp = (float4*)(out + ((size_t)(bt0 + t) * 64 + i) * 64 + j0);
        outp[0] = make_float4(acc[0] * a0.x, acc[1] * a0.y, acc[2] * a0.z, acc[3] * a0.w);
        outp[1] = make_float4(acc[4] * a1.x, acc[5] * a1.y, acc[6] * a1.z, acc[7] * a1.w);
        outp[2] = make_float4(acc[8] * a2.x, acc[9] * a2.y, acc[10] * a2.z, acc[11] * a2.w);
        outp[3] = make_float4(acc[12] * a3.x, acc[13] * a3.y, acc[14] * a3.z, acc[15] * a3.w);
    }
}

extern "C" void kernel_launch(void* const* d_in, const int* in_sizes, int n_in,
                              void* d_out, int out_size, void* d_ws, size_t ws_size,
                              hipStream_t stream) {
    const float* x     = (const float*)d_in[0];
    const float* adj   = (const float*)d_in[1];
    const float* amask = (const float*)d_in[2];
    const float* alpha = (const float*)d_in[3];
    const float* We    = (const float*)d_in[4];
    const float* be    = (const float*)d_in[5];
    const float* Wq    = (const float*)d_in[6];
    const float* Wk    = (const float*)d_in[7];
    float* out = (float*)d_out;

    bfp_kernel<<<2048, 256, 0, stream>>>(x, adj, amask, alpha, We, be, Wq, Wk, out);
}

// Round 14
// 30.167 us; speedup vs baseline: 1.3953x; 1.3953x over previous
//
#include <hip/hip_runtime.h>
#include <math.h>

#define NBANDS 5
#define T_TILE 4
#define PFUNC_ELEMS (32*128*64*64)
#define LOG2E 1.4426950408889634f

typedef __attribute__((ext_vector_type(4))) float f32x4;

// DPP segmented sum over each aligned 8-lane group (VALU pipe, no DS pipe):
//   0xB1 = quad_perm[1,0,3,2] (xor 1), 0x4E = quad_perm[2,3,0,1] (xor 2),
//   0x141 = row_half_mirror (pairs the two quads of each 8-lane group)
#define DPP_ADD(x, ctrl) \
    ((x) + __int_as_float(__builtin_amdgcn_update_dpp(0, __float_as_int(x), (ctrl), 0xF, 0xF, true)))

__global__ __launch_bounds__(512) void bfp_kernel(
        const float* __restrict__ x,      // (32,5,64,128)
        const float* __restrict__ adj,    // (64,64), values in {0,1}
        const float* __restrict__ amask,  // (32,128,5)
        const float* __restrict__ alpha,  // (32,128,5)
        const float* __restrict__ We,     // (5,64)
        const float* __restrict__ be,     // (5,64)
        const float* __restrict__ Wq,     // (16,64)
        const float* __restrict__ Wk,     // (16,64)
        float* __restrict__ out) {
    // 1024 blocks; XCD-bijective swizzle (1024 % 8 == 0)
    const int bid = blockIdx.x;
    const int blk = (bid & 7) * 128 + (bid >> 3);
    const int bt0 = blk * T_TILE;
    const int b = bt0 >> 7;
    const int t0 = bt0 & 127;
    const int tid = threadIdx.x;

    __shared__ __align__(16) float x_s[T_TILE][NBANDS][64];
    __shared__ float xbar_s[T_TILE][NBANDS], xmax_s[T_TILE][NBANDS], xmin_s[T_TILE][NBANDS];
    __shared__ float w_s[T_TILE][NBANDS], mask_s[T_TILE][NBANDS];
    __shared__ float acw_s[NBANDS], bcw_s[NBANDS];

    const int i = tid >> 3;          // output row 0..63
    const int j0 = (tid & 7) << 3;   // first of 8 owned columns

    // adjacency chunk: raw 0/1 floats used as multiplicative mask
    const float4 a0 = *(const float4*)(adj + i * 64 + j0);
    const float4 a1 = *(const float4*)(adj + i * 64 + j0 + 4);

    // issue x staging loads early (waves 0..4)
    float4 xstage;
    if (tid < NBANDS * 64)
        xstage = *(const float4*)(x + ((size_t)b * 320 + tid) * 128 + t0);

    // amask/alpha staging on wave 7 (waves 0-4 run fused prep below)
    if (tid >= 512 - T_TILE * NBANDS) {
        const int idx = tid - (512 - T_TILE * NBANDS);      // 0..19
        const size_t base = ((size_t)b * 128 + t0) * NBANDS;
        const int t = idx / NBANDS, n = idx % NBANDS;
        float mk = amask[base + idx];
        mask_s[t][n] = mk;
        w_s[t][n] = alpha[base + idx] * mk;
    }

    // fused prep: wave w (0..4) computes band w's AC/BC
    {
        const int wvid = tid >> 6;
        const int lane = tid & 63;
        if (wvid < NBANDS) {
            const int n = wvid;
            const int s = lane >> 2;          // d_s index 0..15
            const int d0c = (lane & 3) * 16;  // d-chunk
            float u = 0.f, v = 0.f, w = 0.f;
            #pragma unroll
            for (int dd = 0; dd < 16; ++dd) {
                int d = d0c + dd;
                float we = We[n * 64 + d], bb = be[n * 64 + d];
                float wq = Wq[s * 64 + d], wk = Wk[s * 64 + d];
                u = fmaf(wq, we, u);   // A_s partial
                v = fmaf(wk, we, v);   // C_s partial
                w = fmaf(wq, bb, w);   // B_s partial
            }
            #pragma unroll
            for (int mk = 1; mk <= 2; mk <<= 1) {   // complete quads over d-chunks
                u += __shfl_xor(u, mk);
                v += __shfl_xor(v, mk);
                w += __shfl_xor(w, mk);
            }
            float ac = u * v, bc = w * v;           // A_s*C_s, B_s*C_s
            #pragma unroll
            for (int mk = 4; mk <= 32; mk <<= 1) {  // sum over the 16 s (each once)
                ac += __shfl_xor(ac, mk);
                bc += __shfl_xor(bc, mk);
            }
            if (lane == 0) {
                acw_s[n] = 0.25f * LOG2E * ac;  // 1/sqrt(d_s) * log2e folded
                bcw_s[n] = 0.25f * LOG2E * bc;
            }
        }
    }

    // write staged x to LDS: x_s[t][n][c]
    if (tid < NBANDS * 64) {
        const int n = tid >> 6, c = tid & 63;
        x_s[0][n][c] = xstage.x;
        x_s[1][n][c] = xstage.y;
        x_s[2][n][c] = xstage.z;
        x_s[3][n][c] = xstage.w;
    }
    __syncthreads();

    // per-(t,band) sum/min/max over 64 electrodes; 20 pairs over 8 waves
    {
        const int wv = tid >> 6, lane = tid & 63;
        for (int pair = wv; pair < T_TILE * NBANDS; pair += 8) {
            const int t = pair & 3, n = pair >> 2;
            float v = x_s[t][n][lane];
            float sm = v, mx = v, mn = v;
            #pragma unroll
            for (int mk = 32; mk >= 1; mk >>= 1) {
                sm += __shfl_xor(sm, mk);
                mx = fmaxf(mx, __shfl_xor(mx, mk));
                mn = fminf(mn, __shfl_xor(mn, mk));
            }
            if (lane == 0) {
                xbar_s[t][n] = sm * (1.f / 64.f);
                xmax_s[t][n] = mx;
                xmin_s[t][n] = mn;
            }
        }
    }
    __syncthreads();

    // embeddings_mean for 4 t's (threads 0..255)
    if (tid < T_TILE * 64) {
        const int t = tid >> 6, d = tid & 63;
        float cnt = 0.f, accm = 0.f;
        #pragma unroll
        for (int n = 0; n < NBANDS; ++n) {
            cnt += mask_s[t][n];
            accm += mask_s[t][n] * fmaf(xbar_s[t][n], We[n * 64 + d], be[n * 64 + d]);
        }
        __builtin_nontemporal_store(accm / fmaxf(cnt, 1.f),
                                    out + PFUNC_ELEMS + (size_t)(bt0 + t) * 64 + d);
    }

    for (int t = 0; t < T_TILE; ++t) {
        // burst all LDS reads for this t: 10x ds_read_b128 + 5 scalars in flight
        float4 xv0[NBANDS], xv1[NBANDS];
        float gi[NBANDS];
        #pragma unroll
        for (int n = 0; n < NBANDS; ++n) {
            xv0[n] = ((const float4*)(&x_s[t][n][j0]))[0];
            xv1[n] = ((const float4*)(&x_s[t][n][j0]))[1];
            gi[n]  = x_s[t][n][i];
        }

        float acc[8];
        #pragma unroll
        for (int jj = 0; jj < 8; ++jj) acc[jj] = 0.f;

        #pragma unroll
        for (int n = 0; n < NBANDS; ++n) {
            // base-2 logits coefficient (0.25*log2e folded into acw/bcw)
            const float g2 = fmaf(acw_s[n], gi[n], bcw_s[n]);
            // branchless conservative row bound over ALL j (unmasked exp2 safe)
            const float negm = -fmaxf(g2 * xmax_s[t][n], g2 * xmin_s[t][n]);
            float e0 = __builtin_amdgcn_exp2f(fmaf(g2, xv0[n].x, negm));
            float e1 = __builtin_amdgcn_exp2f(fmaf(g2, xv0[n].y, negm));
            float e2 = __builtin_amdgcn_exp2f(fmaf(g2, xv0[n].z, negm));
            float e3 = __builtin_amdgcn_exp2f(fmaf(g2, xv0[n].w, negm));
            float e4 = __builtin_amdgcn_exp2f(fmaf(g2, xv1[n].x, negm));
            float e5 = __builtin_amdgcn_exp2f(fmaf(g2, xv1[n].y, negm));
            float e6 = __builtin_amdgcn_exp2f(fmaf(g2, xv1[n].z, negm));
            float e7 = __builtin_amdgcn_exp2f(fmaf(g2, xv1[n].w, negm));
            // masked Z via two fma chains (mask folded here, NOT into acc)
            float z0 = e0 * a0.x;
            z0 = fmaf(e1, a0.y, z0);
            z0 = fmaf(e2, a0.z, z0);
            z0 = fmaf(e3, a0.w, z0);
            float z1 = e4 * a1.x;
            z1 = fmaf(e5, a1.y, z1);
            z1 = fmaf(e6, a1.z, z1);
            z1 = fmaf(e7, a1.w, z1);
            float Z = z0 + z1;
            Z = DPP_ADD(Z, 0xB1);    // + lane^1
            Z = DPP_ADD(Z, 0x4E);    // + lane^2
            Z = DPP_ADD(Z, 0x141);   // + mirrored quad (8-lane group total)
            const float sc = w_s[t][n] * __builtin_amdgcn_rcpf(fmaxf(Z, 1e-30f));
            // unmasked accumulate; mask applied once at the store
            acc[0] = fmaf(e0, sc, acc[0]);
            acc[1] = fmaf(e1, sc, acc[1]);
            acc[2] = fmaf(e2, sc, acc[2]);
            acc[3] = fmaf(e3, sc, acc[3]);
            acc[4] = fmaf(e4, sc, acc[4]);
            acc[5] = fmaf(e5, sc, acc[5]);
            acc[6] = fmaf(e6, sc, acc[6]);
            acc[7] = fmaf(e7, sc, acc[7]);
        }

        // apply adjacency mask once, then nontemporal streaming stores
        f32x4* outp = (f32x4*)(out + ((size_t)(bt0 + t) * 64 + i) * 64 + j0);
        f32x4 o0 = {acc[0] * a0.x, acc[1] * a0.y, acc[2] * a0.z, acc[3] * a0.w};
        f32x4 o1 = {acc[4] * a1.x, acc[5] * a1.y, acc[6] * a1.z, acc[7] * a1.w};
        __builtin_nontemporal_store(o0, outp);
        __builtin_nontemporal_store(o1, outp + 1);
    }
}

extern "C" void kernel_launch(void* const* d_in, const int* in_sizes, int n_in,
                              void* d_out, int out_size, void* d_ws, size_t ws_size,
                              hipStream_t stream) {
    const float* x     = (const float*)d_in[0];
    const float* adj   = (const float*)d_in[1];
    const float* amask = (const float*)d_in[2];
    const float* alpha = (const float*)d_in[3];
    const float* We    = (const float*)d_in[4];
    const float* be    = (const float*)d_in[5];
    const float* Wq    = (const float*)d_in[6];
    const float* Wk    = (const float*)d_in[7];
    float* out = (float*)d_out;

    bfp_kernel<<<1024, 512, 0, stream>>>(x, adj, amask, alpha, We, be, Wq, Wk, out);
}